// Round 1
// baseline (126.582 us; speedup 1.0000x reference)
//
#include <hip/hip_runtime.h>
#include <hip/hip_bf16.h>
#include <stdint.h>

#define D_DIM 1024
#define R_DIM 128
#define NIN   8
#define M_TOT 16384
#define K_TOT 8192

typedef unsigned short u16;
typedef __attribute__((ext_vector_type(4))) float f32x4;
typedef __attribute__((ext_vector_type(8))) __bf16 bf16x8;

__device__ __forceinline__ u16 f2b(float f) {
    union { float f; uint32_t u; } v; v.f = f;
    uint32_t r = (v.u + 0x7FFFu + ((v.u >> 16) & 1u)) >> 16;
    return (u16)r;
}

// ---------------- kernel 0: transpose+convert input_neurons [8192][128] f32 -> Bt [128][8192] bf16
__global__ __launch_bounds__(256)
void prep_bt(const float* __restrict__ Bin, u16* __restrict__ Bt) {
    __shared__ float tile[64][65];
    const int k0 = blockIdx.x * 64;   // 128 blocks
    const int r0 = blockIdx.y * 64;   // 2 blocks
    const int tr  = threadIdx.x >> 4;        // 0..15
    const int tc4 = (threadIdx.x & 15) * 4;  // 0..60
#pragma unroll
    for (int p = 0; p < 4; ++p) {
        const int row = p * 16 + tr;
        const f32x4 v = *(const f32x4*)&Bin[(size_t)(k0 + row) * R_DIM + r0 + tc4];
        tile[row][tc4 + 0] = v[0]; tile[row][tc4 + 1] = v[1];
        tile[row][tc4 + 2] = v[2]; tile[row][tc4 + 3] = v[3];
    }
    __syncthreads();
#pragma unroll
    for (int p = 0; p < 4; ++p) {
        const int r = p * 16 + tr;
        ushort4 o;
        o.x = f2b(tile[tc4 + 0][r]);
        o.y = f2b(tile[tc4 + 1][r]);
        o.z = f2b(tile[tc4 + 2][r]);
        o.w = f2b(tile[tc4 + 3][r]);
        *(ushort4*)&Bt[(size_t)(r0 + r) * K_TOT + k0 + tc4] = o;
    }
}

// ---------------- kernel 1: split-K GEMM, y_part[h] = (w .* x) @ A  for n in {2h, 2h+1}
#define BM 128
#define BN 128

__global__ __launch_bounds__(256, 2)
void gemm_part(const float* __restrict__ x, const float* __restrict__ iw,
               const u16* __restrict__ Bt, float* __restrict__ ypart) {
    __shared__ __align__(16) u16 As[BM * 64];   // [128][64] bf16, XOR-swizzled
    __shared__ __align__(16) u16 Bs[BN * 64];   // [col 128][k 64] bf16, XOR-swizzled
    __shared__ float wsm[2 * BM];               // w for the block's two n's

    const int tid  = threadIdx.x;
    const int wid  = tid >> 6;
    const int lane = tid & 63;
    const int m0   = blockIdx.x * BM;
    const int nbase = blockIdx.y * 2;

    // preload w slice: wsm[j*128 + row] = iw[(m0+row)*8 + nbase + j]
    {
        const int j = tid >> 7, row = tid & 127;
        wsm[j * BM + row] = iw[(size_t)(m0 + row) * NIN + nbase + j];
    }

    f32x4 acc[4][4] = {};

    const int wr = wid >> 1, wc = wid & 1;
    const int l15 = lane & 15, lq = lane >> 4;
    const int ac4 = (tid & 15) * 4;   // A staging col
    const int arow_base = tid >> 4;   // A staging row within pass
    const int bc = tid >> 1;          // B staging col (0..127)

    __syncthreads();

    for (int ks = 0; ks < 32; ++ks) {
        const int nl = ks & 1;
        const int d0 = (ks >> 1) * 64;
        const size_t kb = (size_t)(nbase + nl) * D_DIM + d0;

        // ---- stage A: x row-chunk * w -> bf16 LDS (swizzled)
#pragma unroll
        for (int p = 0; p < 8; ++p) {
            const int row = p * 16 + arow_base;
            const f32x4 xv = *(const f32x4*)&x[(size_t)(m0 + row) * D_DIM + d0 + ac4];
            const float wv = wsm[nl * BM + row];
            ushort4 o;
            o.x = f2b(xv[0] * wv); o.y = f2b(xv[1] * wv);
            o.z = f2b(xv[2] * wv); o.w = f2b(xv[3] * wv);
            uint32_t off = (uint32_t)(row * 128 + ac4 * 2);
            off ^= (uint32_t)((row & 7) << 4);
            *(ushort4*)((char*)As + off) = o;
        }
        // ---- stage B: Bt row-chunks -> LDS [col][k] (swizzled)
#pragma unroll
        for (int p = 0; p < 4; ++p) {
            const int chunk = (tid & 1) * 4 + p;  // 0..7 (16B granules of the 128B row)
            const uint4 bv = *(const uint4*)&Bt[(size_t)bc * K_TOT + kb + chunk * 8];
            uint32_t off = (uint32_t)(bc * 128 + chunk * 16);
            off ^= (uint32_t)((bc & 7) << 4);
            *(uint4*)((char*)Bs + off) = bv;
        }
        __syncthreads();

        // ---- compute: 2 kk of 16x16x32, wave-tile 64x64
#pragma unroll
        for (int kk = 0; kk < 2; ++kk) {
            const uint32_t kbyte = (uint32_t)(kk * 64 + lq * 16);
            bf16x8 a[4], b[4];
#pragma unroll
            for (int i = 0; i < 4; ++i) {
                const int row = wr * 64 + i * 16 + l15;
                uint32_t off = (uint32_t)(row * 128) + kbyte;
                off ^= (uint32_t)((row & 7) << 4);
                a[i] = *(const bf16x8*)((const char*)As + off);
            }
#pragma unroll
            for (int i = 0; i < 4; ++i) {
                const int cc = wc * 64 + i * 16 + l15;
                uint32_t off = (uint32_t)(cc * 128) + kbyte;
                off ^= (uint32_t)((cc & 7) << 4);
                b[i] = *(const bf16x8*)((const char*)Bs + off);
            }
#pragma unroll
            for (int i = 0; i < 4; ++i)
#pragma unroll
                for (int j = 0; j < 4; ++j)
                    acc[i][j] = __builtin_amdgcn_mfma_f32_16x16x32_bf16(a[i], b[j], acc[i][j], 0, 0, 0);
        }
        __syncthreads();
    }

    // ---- write partial: C/D layout col=lane&15, row=(lane>>4)*4+reg
    float* yp = ypart + (size_t)blockIdx.y * ((size_t)M_TOT * R_DIM);
#pragma unroll
    for (int i = 0; i < 4; ++i) {
        const int row = m0 + wr * 64 + i * 16 + lq * 4;
#pragma unroll
        for (int j = 0; j < 4; ++j) {
            const int col = wc * 64 + j * 16 + l15;
#pragma unroll
            for (int e = 0; e < 4; ++e)
                yp[(size_t)(row + e) * R_DIM + col] = acc[i][j][e];
        }
    }
}

// ---------------- kernel 2: sum 4 partials + Householder chain + store
__global__ __launch_bounds__(512)
void epilogue(const float* __restrict__ ypart, const int* __restrict__ pidx,
              const float* __restrict__ pn, float* __restrict__ out) {
    const int tid = threadIdx.x;
    const int row = tid >> 3;       // 0..63
    const int cg  = tid & 7;        // 8 threads per token
    const int c0  = cg * 16;
    const int tok = blockIdx.x * 64 + row;

    float y[16];
#pragma unroll
    for (int q = 0; q < 4; ++q) {
        f32x4 s = *(const f32x4*)&ypart[(size_t)tok * R_DIM + c0 + q * 4];
#pragma unroll
        for (int h = 1; h < 4; ++h)
            s += *(const f32x4*)&ypart[(size_t)h * M_TOT * R_DIM + (size_t)tok * R_DIM + c0 + q * 4];
        y[q * 4 + 0] = s[0]; y[q * 4 + 1] = s[1]; y[q * 4 + 2] = s[2]; y[q * 4 + 3] = s[3];
    }

    const int4 idx4 = *(const int4*)&pidx[tok * 4];
    const int idxs[4] = { idx4.x, idx4.y, idx4.z, idx4.w };

#pragma unroll
    for (int k = 0; k < 4; ++k) {
        const float* vptr = &pn[(size_t)idxs[k] * R_DIM + c0];
        float v[16];
#pragma unroll
        for (int q = 0; q < 4; ++q) {
            const f32x4 vv4 = *(const f32x4*)&vptr[q * 4];
            v[q * 4 + 0] = vv4[0]; v[q * 4 + 1] = vv4[1];
            v[q * 4 + 2] = vv4[2]; v[q * 4 + 3] = vv4[3];
        }
        float vy = 0.f, vv = 0.f;
#pragma unroll
        for (int j = 0; j < 16; ++j) { vy += v[j] * y[j]; vv += v[j] * v[j]; }
#pragma unroll
        for (int o = 1; o < 8; o <<= 1) {
            vy += __shfl_xor(vy, o);
            vv += __shfl_xor(vv, o);
        }
        const float s = 2.0f * vy / (vv + 1e-8f);
#pragma unroll
        for (int j = 0; j < 16; ++j) y[j] -= s * v[j];
    }

#pragma unroll
    for (int q = 0; q < 4; ++q) {
        f32x4 o; o[0] = y[q*4+0]; o[1] = y[q*4+1]; o[2] = y[q*4+2]; o[3] = y[q*4+3];
        *(f32x4*)&out[(size_t)tok * R_DIM + c0 + q * 4] = o;
    }
}

extern "C" void kernel_launch(void* const* d_in, const int* in_sizes, int n_in,
                              void* d_out, int out_size, void* d_ws, size_t ws_size,
                              hipStream_t stream) {
    const float* x   = (const float*)d_in[0];   // [4,4096,1024]
    const float* iw  = (const float*)d_in[1];   // [4,4096,8]
    const int*   pix = (const int*)d_in[2];     // [4,4096,4]
    const float* inn = (const float*)d_in[3];   // [8,1024,128]
    const float* pn  = (const float*)d_in[4];   // [32,128]
    float* out = (float*)d_out;                 // [4,4096,128] f32

    u16*   Bt    = (u16*)d_ws;                             // 2 MB
    float* ypart = (float*)((char*)d_ws + (size_t)(2 << 20)); // 4 x 8 MB

    prep_bt<<<dim3(128, 2), 256, 0, stream>>>(inn, Bt);
    gemm_part<<<dim3(128, 4), 256, 0, stream>>>(x, iw, Bt, ypart);
    epilogue<<<256, 512, 0, stream>>>(ypart, pix, pn, out);
}

// Round 2
// 64.138 us; speedup vs baseline: 1.9736x; 1.9736x over previous
//
#include <hip/hip_runtime.h>
#include <hip/hip_bf16.h>
#include <stdint.h>

#define D_DIM 1024
#define R_DIM 128
#define NIN   8
#define M_TOT 16384

typedef unsigned short u16;
typedef __attribute__((ext_vector_type(4))) float f32x4;
typedef __attribute__((ext_vector_type(8))) __bf16 bf16x8;

__device__ __forceinline__ u16 f2b(float f) {
    union { float f; uint32_t u; } v; v.f = f;
    uint32_t r = (v.u + 0x7FFFu + ((v.u >> 16) & 1u)) >> 16;
    return (u16)r;
}

__device__ __forceinline__ void gload16(const void* g, void* l) {
    __builtin_amdgcn_global_load_lds(
        (const __attribute__((address_space(1))) uint32_t*)g,
        (__attribute__((address_space(3))) uint32_t*)l, 16, 0, 0);
}

// ---------------- kernel 0a: x f32 -> bf16 (plain layout)
__global__ __launch_bounds__(256)
void prep_x(const float* __restrict__ x, u16* __restrict__ xb) {
    const size_t i = ((size_t)blockIdx.x * 256 + threadIdx.x) * 8;
    const f32x4 v0 = *(const f32x4*)&x[i];
    const f32x4 v1 = *(const f32x4*)&x[i + 4];
    union { u16 s[8]; uint4 v; } u;
#pragma unroll
    for (int q = 0; q < 4; ++q) { u.s[q] = f2b(v0[q]); u.s[4 + q] = f2b(v1[q]); }
    *(uint4*)&xb[i] = u.v;
}

// ---------------- kernel 0b: input_neurons [8][1024][128] f32 -> Bt2 [1024][1024] bf16
// Bt2 row C = (r>>4)*128 + n*16 + (r&15), contents = inn[n][d][r] over d
__global__ __launch_bounds__(128)
void prep_b(const float* __restrict__ inn, u16* __restrict__ Bt2) {
    const int n  = blockIdx.x;        // 0..7
    const int d0 = blockIdx.y * 64;   // 16 chunks
    const int r  = threadIdx.x;       // 0..127
    const size_t C = (size_t)((r >> 4) * 128 + n * 16 + (r & 15));
#pragma unroll
    for (int g = 0; g < 8; ++g) {
        union { u16 s[8]; uint4 v; } u;
#pragma unroll
        for (int jj = 0; jj < 8; ++jj)
            u.s[jj] = f2b(inn[((size_t)n * D_DIM + d0 + g * 8 + jj) * R_DIM + r]);
        *(uint4*)&Bt2[C * D_DIM + d0 + g * 8] = u.v;
    }
}

// ---------------- kernel 1: fused GEMM + w-reduction over n
// grid 1024: bx (M/128) x by (R/16).  local col cc = n*16 + rr, n=cc>>4, rr=cc&15
__global__ __launch_bounds__(256, 4)
void gemm_fused(const u16* __restrict__ xb, const u16* __restrict__ Bt2,
                const float* __restrict__ iw, float* __restrict__ y) {
    __shared__ __align__(16) u16 As[128 * 64];
    __shared__ __align__(16) u16 Bs[128 * 64];
    __shared__ __align__(16) float wsm[128 * 8];

    const int tid  = threadIdx.x;
    const int wid  = tid >> 6, lane = tid & 63;
    const int wr = wid >> 1, wc = wid & 1;
    const int l15 = lane & 15, lq = lane >> 4;

    // XCD-aware bijective swizzle (nwg=1024, %8==0)
    int wg = (int)blockIdx.x;
    wg = (wg & 7) * 128 + (wg >> 3);
    const int by = wg & 7;
    const int bx = wg >> 3;
    const int m0 = bx * 128;
    const int c0 = by * 128;

    // preload w slice [128][8] into LDS
    *(f32x4*)&wsm[tid * 4] = *(const f32x4*)&iw[(size_t)m0 * NIN + tid * 4];

    // staging source addresses (inverse-swizzled so linear LDS + swizzled read works)
    const int srow = tid >> 3;             // row within a 32-row issue group
    const int sby  = (tid & 7) * 16;       // posbyte within the 128B row chunk
    const int sxor = sby ^ ((srow & 7) << 4);
    const char* gA = (const char*)xb  + ((size_t)(m0 + srow) * D_DIM) * 2 + sxor;
    const char* gB = (const char*)Bt2 + ((size_t)(c0 + srow) * D_DIM) * 2 + sxor;

    f32x4 acc[4][4] = {};

    for (int ks = 0; ks < 16; ++ks) {
        const int doff = ks * 128;   // d0 * 2 bytes
#pragma unroll
        for (int p = 0; p < 4; ++p) {
            gload16(gA + (size_t)p * (32 * 2048) + doff, (char*)As + p * 4096 + tid * 16);
            gload16(gB + (size_t)p * (32 * 2048) + doff, (char*)Bs + p * 4096 + tid * 16);
        }
        __syncthreads();

#pragma unroll
        for (int kk = 0; kk < 2; ++kk) {
            const uint32_t kbyte = (uint32_t)(kk * 64 + lq * 16);
            bf16x8 a[4], b[4];
#pragma unroll
            for (int i = 0; i < 4; ++i) {
                const int row = wr * 64 + i * 16 + l15;
                uint32_t off = (uint32_t)(row * 128) + kbyte;
                off ^= (uint32_t)((row & 7) << 4);
                a[i] = *(const bf16x8*)((const char*)As + off);
            }
#pragma unroll
            for (int i = 0; i < 4; ++i) {
                const int cc = wc * 64 + i * 16 + l15;
                uint32_t off = (uint32_t)(cc * 128) + kbyte;
                off ^= (uint32_t)((cc & 7) << 4);
                b[i] = *(const bf16x8*)((const char*)Bs + off);
            }
#pragma unroll
            for (int i = 0; i < 4; ++i)
#pragma unroll
                for (int j = 0; j < 4; ++j)
                    acc[i][j] = __builtin_amdgcn_mfma_f32_16x16x32_bf16(a[i], b[j], acc[i][j], 0, 0, 0);
        }
        __syncthreads();
    }

    // ---- epilogue: n = wc*4 + j (register index), rr = l15
    // own[i][e] = sum_j w[row][wc*4+j] * acc[i][j][e]
    float own[4][4];
#pragma unroll
    for (int i = 0; i < 4; ++i)
#pragma unroll
        for (int e = 0; e < 4; ++e) {
            const int row = wr * 64 + i * 16 + lq * 4 + e;
            float s = 0.f;
#pragma unroll
            for (int j = 0; j < 4; ++j)
                s += wsm[row * NIN + wc * 4 + j] * acc[i][j][e];
            own[i][e] = s;
        }

    float* pr = (float*)As;  // alias: [128][17] f32 (8.7 KB < 16 KB)
    if (wc == 1) {
#pragma unroll
        for (int i = 0; i < 4; ++i)
#pragma unroll
            for (int e = 0; e < 4; ++e) {
                const int row = wr * 64 + i * 16 + lq * 4 + e;
                pr[row * 17 + l15] = own[i][e];
            }
    }
    __syncthreads();
    if (wc == 0) {
#pragma unroll
        for (int i = 0; i < 4; ++i)
#pragma unroll
            for (int e = 0; e < 4; ++e) {
                const int row = wr * 64 + i * 16 + lq * 4 + e;
                const float s = own[i][e] + pr[row * 17 + l15];
                y[(size_t)(m0 + row) * R_DIM + by * 16 + l15] = s;
            }
    }
}

// ---------------- kernel 2: Householder chain, in-place on d_out
__global__ __launch_bounds__(512)
void house(float* __restrict__ y, const int* __restrict__ pidx,
           const float* __restrict__ pn) {
    const int tid = threadIdx.x;
    const int row = tid >> 3;
    const int cg  = tid & 7;
    const int c0  = cg * 16;
    const int tok = blockIdx.x * 64 + row;

    float yv[16];
#pragma unroll
    for (int q = 0; q < 4; ++q) {
        const f32x4 s = *(const f32x4*)&y[(size_t)tok * R_DIM + c0 + q * 4];
        yv[q * 4 + 0] = s[0]; yv[q * 4 + 1] = s[1]; yv[q * 4 + 2] = s[2]; yv[q * 4 + 3] = s[3];
    }

    const int4 idx4 = *(const int4*)&pidx[tok * 4];
    const int idxs[4] = { idx4.x, idx4.y, idx4.z, idx4.w };

#pragma unroll
    for (int k = 0; k < 4; ++k) {
        const float* vptr = &pn[(size_t)idxs[k] * R_DIM + c0];
        float v[16];
#pragma unroll
        for (int q = 0; q < 4; ++q) {
            const f32x4 vv4 = *(const f32x4*)&vptr[q * 4];
            v[q * 4 + 0] = vv4[0]; v[q * 4 + 1] = vv4[1];
            v[q * 4 + 2] = vv4[2]; v[q * 4 + 3] = vv4[3];
        }
        float vy = 0.f, vv = 0.f;
#pragma unroll
        for (int j = 0; j < 16; ++j) { vy += v[j] * yv[j]; vv += v[j] * v[j]; }
#pragma unroll
        for (int o = 1; o < 8; o <<= 1) {
            vy += __shfl_xor(vy, o);
            vv += __shfl_xor(vv, o);
        }
        const float s = 2.0f * vy / (vv + 1e-8f);
#pragma unroll
        for (int j = 0; j < 16; ++j) yv[j] -= s * v[j];
    }

#pragma unroll
    for (int q = 0; q < 4; ++q) {
        f32x4 o; o[0] = yv[q*4+0]; o[1] = yv[q*4+1]; o[2] = yv[q*4+2]; o[3] = yv[q*4+3];
        *(f32x4*)&y[(size_t)tok * R_DIM + c0 + q * 4] = o;
    }
}

extern "C" void kernel_launch(void* const* d_in, const int* in_sizes, int n_in,
                              void* d_out, int out_size, void* d_ws, size_t ws_size,
                              hipStream_t stream) {
    const float* x   = (const float*)d_in[0];   // [4,4096,1024]
    const float* iw  = (const float*)d_in[1];   // [4,4096,8]
    const int*   pix = (const int*)d_in[2];     // [4,4096,4]
    const float* inn = (const float*)d_in[3];   // [8,1024,128]
    const float* pn  = (const float*)d_in[4];   // [32,128]
    float* out = (float*)d_out;                 // [4,4096,128] f32

    u16* xb  = (u16*)d_ws;                                  // 32 MB
    u16* Bt2 = (u16*)((char*)d_ws + (size_t)(32 << 20));    // 2 MB

    prep_x<<<8192, 256, 0, stream>>>(x, xb);
    prep_b<<<dim3(8, 16), 128, 0, stream>>>(inn, Bt2);
    gemm_fused<<<1024, 256, 0, stream>>>(xb, Bt2, iw, out);
    house<<<256, 512, 0, stream>>>(out, pix, pn);
}